// Round 5
// baseline (1324.502 us; speedup 1.0000x reference)
//
#include <hip/hip_runtime.h>
#include <hip/hip_bf16.h>

#define TB 4
#define TN 640
#define TC 1024
#define TH 16
#define THD 64
#define TI 4096
#define TE 8
#define TT (TB*TN)     /* 2560 tokens */
#define TBH (TB*TH)    /* 64 */
#define SCALE_ 0.125f

typedef unsigned short u16;
typedef __bf16 bf16x8 __attribute__((ext_vector_type(8)));
typedef float f32x4 __attribute__((ext_vector_type(4)));

// ---------------------------------------------------------------------------
// bf16 MFMA GEMM, m97 structure: BK=32, single 16KB LDS buffer, __syncthreads,
// compiler-managed waitcnt. Both operands staged via global_load_lds w=16.
// Bijective XCD swizzle + y-fastest decode for weight L2 reuse.
// EPI: 0=store f32, 1=store bf16 (row aoff+i), 2=resadd x += v*scalevec
//      (non-atomic RMW), 3=gelu->bf16 (row aoff+i)
// Routed mode (counts != nullptr): per-z count/offset, gather rows via idx.
// ---------------------------------------------------------------------------
template<int BM, int BN, bool GATHER, int EPI>
__global__ __launch_bounds__(256) void gemm_bt(
    const u16* __restrict__ A, const u16* __restrict__ Wb, void* __restrict__ Cout,
    const float* __restrict__ bias, long biasStride,
    const float* __restrict__ scalevec,
    const int* __restrict__ idxList, long idxStride,
    const int* __restrict__ counts, const int* __restrict__ offsets,
    int M, int Kfull, int nby, int ldc,
    long sA, long sW, long sCo, long sCi, int Z2)
{
  constexpr int FM = BM/32, FN = BN/32;
  constexpr int AI = BM/64, BI = BN/64;   // 16-row chunk loads per wave

  const int ze = blockIdx.z;

  // bijective XCD swizzle (m204) + y-fastest decode for weight L2 reuse
  const int nwg = gridDim.x;
  int lin = blockIdx.x;
  int q = nwg >> 3, r = nwg & 7;
  int xcd = lin & 7, pos = lin >> 3;
  int swz = (xcd < r ? xcd*(q+1) : r*(q+1) + (xcd-r)*q) + pos;
  const int bx = swz / nby;
  const int by = swz - bx*nby;

  int mcount = M, aoff = 0;
  if (counts){ mcount = counts[ze]; aoff = offsets ? offsets[ze] : 0; }
  if (by*BM >= mcount) return;

  const int tid = threadIdx.x, w = tid>>6, lane = tid&63;
  const int wm = w>>1, wn = w&1;

  __shared__ __align__(16) u16 As[BM*32];
  __shared__ __align__(16) u16 Bs[BN*32];

  const u16* Az = A + (long)ze*sA;
  const u16* Wz = Wb + (long)ze*sW;
  const int* idx_z = idxList ? (idxList + (long)ze*idxStride) : nullptr;

  long a_src[AI];
  #pragma unroll
  for (int j=0;j<AI;j++){
    int i = by*BM + (w*AI+j)*16 + (lane>>2);
    int row;
    if (counts){
      int ie = (i < mcount) ? i : (mcount-1);
      row = GATHER ? idx_z[ie] : (aoff + ie);
    } else row = i;
    a_src[j] = (long)row*Kfull + (lane&3)*8;
  }
  long b_src[BI];
  #pragma unroll
  for (int j=0;j<BI;j++){
    int rr = bx*BN + (w*BI+j)*16 + (lane>>2);
    b_src[j] = (long)rr*Kfull + (lane&3)*8;
  }

  f32x4 acc[FM][FN];
  #pragma unroll
  for (int m=0;m<FM;m++)
    #pragma unroll
    for (int n=0;n<FN;n++) acc[m][n] = (f32x4){0.f,0.f,0.f,0.f};

  for (int k0=0; k0<Kfull; k0+=32){
    #pragma unroll
    for (int j=0;j<AI;j++)
      __builtin_amdgcn_global_load_lds(
        (const __attribute__((address_space(1))) void*)(Az + a_src[j] + k0),
        (__attribute__((address_space(3))) void*)(&As[(w*AI+j)*512]), 16, 0, 0);
    #pragma unroll
    for (int j=0;j<BI;j++)
      __builtin_amdgcn_global_load_lds(
        (const __attribute__((address_space(1))) void*)(Wz + b_src[j] + k0),
        (__attribute__((address_space(3))) void*)(&Bs[(w*BI+j)*512]), 16, 0, 0);
    __syncthreads();
    bf16x8 af[FM], bfr[FN];
    #pragma unroll
    for (int m=0;m<FM;m++)
      af[m] = *reinterpret_cast<const bf16x8*>(&As[(wm*(BM/2)+m*16+(lane&15))*32 + (lane>>4)*8]);
    #pragma unroll
    for (int n=0;n<FN;n++)
      bfr[n] = *reinterpret_cast<const bf16x8*>(&Bs[(wn*(BN/2)+n*16+(lane&15))*32 + (lane>>4)*8]);
    #pragma unroll
    for (int m=0;m<FM;m++)
      #pragma unroll
      for (int n=0;n<FN;n++)
        acc[m][n] = __builtin_amdgcn_mfma_f32_16x16x32_bf16(af[m], bfr[n], acc[m][n], 0, 0, 0);
    __syncthreads();
  }

  const float* bz = bias ? (bias + (long)ze*biasStride) : nullptr;
  long csel = (long)(ze/Z2)*sCo + (long)(ze%Z2)*sCi;
  #pragma unroll
  for (int m=0;m<FM;m++){
    #pragma unroll
    for (int n=0;n<FN;n++){
      int gcol = bx*BN + wn*(BN/2) + n*16 + (lane&15);
      float bv = bz ? bz[gcol] : 0.f;
      #pragma unroll
      for (int jj=0;jj<4;jj++){
        int i = by*BM + wm*(BM/2) + m*16 + (lane>>4)*4 + jj;
        if (counts && i >= mcount) continue;
        float v = acc[m][n][jj] + bv;
        if constexpr (EPI == 0){
          ((float*)Cout)[csel + (long)i*ldc + gcol] = v;
        } else if constexpr (EPI == 1){
          ((__hip_bfloat16*)Cout)[csel + (long)(aoff+i)*ldc + gcol] = __float2bfloat16(v);
        } else if constexpr (EPI == 2){
          float* p = (float*)Cout + csel + (long)i*ldc + gcol;
          *p += v * scalevec[gcol];
        } else { // EPI == 3
          float g = 0.5f*v*(1.f + erff(v*0.70710678118654752f));
          ((__hip_bfloat16*)Cout)[csel + (long)(aoff+i)*ldc + gcol] = __float2bfloat16(g);
        }
      }
    }
  }
}

// ---------------------------------------------------------------------------
__global__ __launch_bounds__(256) void cvt_kernel(const float* __restrict__ s,
    u16* __restrict__ d, long n)
{
  long i = ((long)blockIdx.x*256 + threadIdx.x)*8;
  if (i >= n) return;
  float4 a = *(const float4*)(s+i);
  float4 b = *(const float4*)(s+i+4);
  union { __hip_bfloat162 h[4]; uint4 v; } o;
  o.h[0] = __float22bfloat162_rn(make_float2(a.x,a.y));
  o.h[1] = __float22bfloat162_rn(make_float2(a.z,a.w));
  o.h[2] = __float22bfloat162_rn(make_float2(b.x,b.y));
  o.h[3] = __float22bfloat162_rn(make_float2(b.z,b.w));
  *(uint4*)(d+i) = o.v;
}

__global__ __launch_bounds__(256) void init_x_kernel(const float* __restrict__ h,
    float* __restrict__ x, int n)
{
  int i = blockIdx.x*256 + threadIdx.x;
  if (i < n) x[i] = h[i];
  else if (i == n) x[i] = 0.f;   // aux slot
}

__global__ __launch_bounds__(256) void ln_kernel(const float* __restrict__ x,
    const float* __restrict__ s, const float* __restrict__ b,
    float* __restrict__ of, __hip_bfloat16* __restrict__ ob)
{
  int row = blockIdx.x, tid = threadIdx.x;
  const float* xr = x + (long)row*TC;
  int c = tid*4;
  float4 xv = *(const float4*)(xr + c);
  float sum = xv.x+xv.y+xv.z+xv.w;
  float sq = xv.x*xv.x+xv.y*xv.y+xv.z*xv.z+xv.w*xv.w;
  #pragma unroll
  for (int o=32;o;o>>=1){ sum += __shfl_down(sum,o); sq += __shfl_down(sq,o); }
  __shared__ float ls[8];
  if ((tid&63)==0){ ls[tid>>6] = sum; ls[4+(tid>>6)] = sq; }
  __syncthreads();
  float mean = (ls[0]+ls[1]+ls[2]+ls[3]) * (1.f/TC);
  float ex2  = (ls[4]+ls[5]+ls[6]+ls[7]) * (1.f/TC);
  float rstd = rsqrtf(ex2 - mean*mean + 1e-6f);
  float4 sv = *(const float4*)(s + c);
  float4 bv = *(const float4*)(b + c);
  float o0 = (xv.x-mean)*rstd*sv.x + bv.x;
  float o1 = (xv.y-mean)*rstd*sv.y + bv.y;
  float o2 = (xv.z-mean)*rstd*sv.z + bv.z;
  float o3 = (xv.w-mean)*rstd*sv.w + bv.w;
  *(float4*)(of + (long)row*TC + c) = make_float4(o0,o1,o2,o3);
  __hip_bfloat16* op = ob + (long)row*TC + c;
  *reinterpret_cast<__hip_bfloat162*>(op)   = __float22bfloat162_rn(make_float2(o0,o1));
  *reinterpret_cast<__hip_bfloat162*>(op+2) = __float22bfloat162_rn(make_float2(o2,o3));
}

__global__ void build_qkv_bias(const float* __restrict__ qb, const float* __restrict__ vb,
    float* __restrict__ out)
{
  int i = blockIdx.x*256 + threadIdx.x;
  if (i >= 3*TC) return;
  float v = 0.f;
  if (i < TC) v = qb[i];
  else if (i >= 2*TC) v = vb[i-2*TC];
  out[i] = v;
}

// grid (TN/128, TBH): copy q,k sections; LDS-transpose v into vT[bh][d][n]
__global__ __launch_bounds__(256) void qkv_reshape(const u16* __restrict__ qkv,
    u16* __restrict__ q, u16* __restrict__ k, u16* __restrict__ vT)
{
  const int bh = blockIdx.y, b = bh>>4, h = bh&15;
  const int n0 = blockIdx.x*128;
  const int tid = threadIdx.x;
  const long rowbase = ((long)b*TN + n0)*(3*TC) + h*THD;
  __shared__ u16 vt[128][72];
  #pragma unroll
  for (int j=0;j<4;j++){
    int f = j*2048 + tid*8;
    int r = f>>6, d = f&63;
    long src = rowbase + (long)r*(3*TC) + d;
    long dst = ((long)bh*TN + n0 + r)*THD + d;
    *(uint4*)(q + dst) = *(const uint4*)(qkv + src);
    *(uint4*)(k + dst) = *(const uint4*)(qkv + src + TC);
    *(uint4*)(&vt[r][d]) = *(const uint4*)(qkv + src + 2*TC);
  }
  __syncthreads();
  #pragma unroll
  for (int j=0;j<4;j++){
    int f = j*2048 + tid*8;
    int dr = f>>7, nc = f&127;
    union { uint4 v; u16 u[8]; } o;
    #pragma unroll
    for (int e=0;e<8;e++) o.u[e] = vt[nc+e][dr];
    *(uint4*)(vT + ((long)bh*THD + dr)*TN + n0 + nc) = o.v;
  }
}

__global__ __launch_bounds__(256) void softmax_kernel(const float* __restrict__ S,
    const float* __restrict__ rpb, const int* __restrict__ mask, __hip_bfloat16* __restrict__ P)
{
  int row = blockIdx.x, tid = threadIdx.x;
  int qpos = row % TN;
  int bh = row / TN;
  int h = bh & (TH-1);
  int b = bh >> 4;
  const float* srow = S + (long)row*TN;
  const float* rrow = rpb + ((long)h*TN + qpos)*TN;
  const int* mrow = mask + b*TN;
  float v[3];
  float mx = -3e38f;
  #pragma unroll
  for (int j=0;j<3;j++){
    int kk = tid + j*256;
    float t = -3e38f;
    if (kk < TN){
      t = srow[kk]*SCALE_ + rrow[kk];
      if (mrow[kk] == 0) t = -1e30f;
    }
    v[j] = t;
    mx = fmaxf(mx, t);
  }
  #pragma unroll
  for (int o=32;o;o>>=1) mx = fmaxf(mx, __shfl_down(mx,o));
  __shared__ float ls[4], ls2[4];
  if ((tid&63)==0) ls[tid>>6] = mx;
  __syncthreads();
  mx = fmaxf(fmaxf(ls[0],ls[1]), fmaxf(ls[2],ls[3]));
  float sum = 0.f;
  #pragma unroll
  for (int j=0;j<3;j++){
    int kk = tid + j*256;
    if (kk < TN){ v[j] = __expf(v[j]-mx); sum += v[j]; }
  }
  #pragma unroll
  for (int o=32;o;o>>=1) sum += __shfl_down(sum,o);
  if ((tid&63)==0) ls2[tid>>6] = sum;
  __syncthreads();
  float inv = 1.f/(ls2[0]+ls2[1]+ls2[2]+ls2[3]);
  #pragma unroll
  for (int j=0;j<3;j++){
    int kk = tid + j*256;
    if (kk < TN) P[(long)row*TN + kk] = __float2bfloat16(v[j]*inv);
  }
}

__global__ __launch_bounds__(256) void gate_kernel(const float* __restrict__ ln,
    const float* __restrict__ gw, float* __restrict__ logits)
{
  int t = blockIdx.x, tid = threadIdx.x;
  int c = tid*4;
  float4 xv = *(const float4*)(ln + (long)t*TC + c);
  __shared__ float ls[4];
  for (int e=0;e<TE;e++){
    float4 wv = *(const float4*)(gw + (long)e*TC + c);
    float p = xv.x*wv.x + xv.y*wv.y + xv.z*wv.z + xv.w*wv.w;
    #pragma unroll
    for (int o=32;o;o>>=1) p += __shfl_down(p,o);
    if ((tid&63)==0) ls[tid>>6] = p;
    __syncthreads();
    if (tid==0) logits[(long)t*TE + e] = ls[0]+ls[1]+ls[2]+ls[3];
    __syncthreads();
  }
}

__global__ __launch_bounds__(256) void routing_kernel(const float* __restrict__ logits,
    int* __restrict__ counts, int* __restrict__ etok,
    int* __restrict__ tE, int* __restrict__ tP, float* __restrict__ tG,
    float* __restrict__ psum)
{
  __shared__ float ps[TE];
  int tid = threadIdx.x;
  if (tid < TE) ps[tid] = 0.f;
  __syncthreads();
  int t = blockIdx.x*256 + tid;
  if (t < TT){
    float pr[TE]; float mx = -3e38f;
    #pragma unroll
    for (int e=0;e<TE;e++){ pr[e] = logits[(long)t*TE+e]; mx = fmaxf(mx, pr[e]); }
    float sum = 0.f;
    #pragma unroll
    for (int e=0;e<TE;e++){ pr[e] = __expf(pr[e]-mx); sum += pr[e]; }
    float inv = 1.f/sum;
    #pragma unroll
    for (int e=0;e<TE;e++) pr[e] *= inv;
    int i1 = 0;
    #pragma unroll
    for (int e=1;e<TE;e++) if (pr[e] > pr[i1]) i1 = e;
    int i2 = -1;
    #pragma unroll
    for (int e=0;e<TE;e++){ if (e==i1) continue; if (i2<0 || pr[e]>pr[i2]) i2=e; }
    float p1 = pr[i1], p2 = pr[i2];
    float g1 = p1/(p1+p2), g2 = p2/(p1+p2);
    int pos1 = atomicAdd(&counts[i1], 1);
    etok[i1*TT + pos1] = t;
    int pos2 = atomicAdd(&counts[i2], 1);
    etok[i2*TT + pos2] = t;
    tE[2*t] = i1; tP[2*t] = pos1; tG[2*t] = g1;
    tE[2*t+1] = i2; tP[2*t+1] = pos2; tG[2*t+1] = g2;
    #pragma unroll
    for (int e=0;e<TE;e++) atomicAdd(&ps[e], pr[e]);
  }
  __syncthreads();
  if (tid < TE) atomicAdd(&psum[tid], ps[tid]);
}

__global__ void finalize_routing(const int* __restrict__ counts, int* __restrict__ offsets,
    const float* __restrict__ psum, float* __restrict__ aux)
{
  int off = 0; float a = 0.f;
  for (int e=0;e<TE;e++){
    offsets[e] = off; off += counts[e];
    a += (psum[e]*(1.f/TT)) * ((float)counts[e]*(1.f/TT));
  }
  aux[0] += (float)TE * a;
}

// x[t] += (g1*y[slot1] + g2*y[slot2]) * gamma2   (grid TT, 256 thr, 4 col/thr)
__global__ __launch_bounds__(256) void combine_kernel(
    const u16* __restrict__ y, const int* __restrict__ tE, const int* __restrict__ tP,
    const float* __restrict__ tG, const int* __restrict__ offsets,
    const float* __restrict__ gamma2, float* __restrict__ x)
{
  int t = blockIdx.x, c = threadIdx.x*4;
  int e1 = tE[2*t], e2 = tE[2*t+1];
  long s1 = (long)(offsets[e1]+tP[2*t])*TC + c;
  long s2 = (long)(offsets[e2]+tP[2*t+1])*TC + c;
  float g1 = tG[2*t], g2 = tG[2*t+1];
  ushort4 y1 = *(const ushort4*)(y+s1);
  ushort4 y2 = *(const ushort4*)(y+s2);
  float4 gv = *(const float4*)(gamma2 + c);
  float* xp = x + (long)t*TC + c;
  float4 xv = *(const float4*)xp;
  auto b2f = [](u16 u){ union{float f;unsigned i;} v; v.i = (unsigned)u<<16; return v.f; };
  xv.x += (g1*b2f(y1.x) + g2*b2f(y2.x))*gv.x;
  xv.y += (g1*b2f(y1.y) + g2*b2f(y2.y))*gv.y;
  xv.z += (g1*b2f(y1.z) + g2*b2f(y2.z))*gv.z;
  xv.w += (g1*b2f(y1.w) + g2*b2f(y2.w))*gv.w;
  *(float4*)xp = xv;
}

// ---------------------------------------------------------------------------
extern "C" void kernel_launch(void* const* d_in, const int* in_sizes, int n_in,
                              void* d_out, int out_size, void* d_ws, size_t ws_size,
                              hipStream_t stream) {
  (void)in_sizes; (void)n_in; (void)out_size; (void)ws_size;
  const float* hidden = (const float*)d_in[0];
  const int*   amask  = (const int*)d_in[1];
  const float* rpb    = (const float*)d_in[2];
  const float* qkv_w  = (const float*)d_in[3];
  const float* q_bias = (const float*)d_in[4];
  const float* v_bias = (const float*)d_in[5];
  const float* proj_w = (const float*)d_in[6];
  const float* proj_b = (const float*)d_in[7];
  const float* ln1_s  = (const float*)d_in[8];
  const float* ln1_b  = (const float*)d_in[9];
  const float* ln2_s  = (const float*)d_in[10];
  const float* ln2_b  = (const float*)d_in[11];
  const float* gamma1 = (const float*)d_in[12];
  const float* gamma2 = (const float*)d_in[13];
  const float* gate_w = (const float*)d_in[14];
  const float* fc1_w  = (const float*)d_in[15];
  const float* fc1_b  = (const float*)d_in[16];
  const float* fc2_w  = (const float*)d_in[17];
  const float* fc2_b  = (const float*)d_in[18];

  float* x = (float*)d_out;
  const int NXC = TT*TC;

  char* p = (char*)d_ws;
  auto alloc = [&](size_t bytes)->void* {
    void* r = (void*)p; p += (bytes + 255) & ~(size_t)255; return r;
  };
  float* qkvbias = (float*)alloc(3*TC*4);
  u16*   ln_bf   = (u16*)alloc((size_t)TT*TC*2);
  float* ln_f    = (float*)alloc((size_t)TT*TC*4);
  float* logits  = (float*)alloc((size_t)TT*TE*4);
  int*   counts  = (int*)alloc(TE*4);
  int*   offsets = (int*)alloc(TE*4);
  float* psum    = (float*)alloc(TE*4);
  int*   etok    = (int*)alloc((size_t)TE*TT*4);
  int*   tE      = (int*)alloc((size_t)2*TT*4);
  int*   tP      = (int*)alloc((size_t)2*TT*4);
  float* tG      = (float*)alloc((size_t)2*TT*4);
  char* arena = (char*)alloc(202375168);
  // attention phase
  float* scores  = (float*)(arena);                         // 104,857,600
  u16*   Pb      = (u16*)(arena + 104857600);               //  52,428,800
  u16*   qkv_bf  = (u16*)(arena + 157286400);               //  15,728,640
  u16*   qb      = (u16*)(arena + 173015040);               //   5,242,880
  u16*   kb      = (u16*)(arena + 178257920);               //   5,242,880
  u16*   vT      = (u16*)(arena + 183500800);               //   5,242,880
  u16*   attn_o  = (u16*)(arena + 188743680);               //   5,242,880
  u16*   wqkv    = (u16*)(arena + 193986560);               //   6,291,456
  u16*   wproj   = (u16*)(arena + 200278016);               //   2,097,152
  // MoE phase (overlays attention-phase buffers — dead by then)
  u16*   fc1b    = (u16*)(arena);                           //  67,108,864
  u16*   fc2b    = (u16*)(arena + 67108864);                //  67,108,864
  u16*   h1      = (u16*)(arena + 134217728);               //  41,943,040 (2*TT x TI bf16)
  u16*   yslot   = (u16*)(arena + 176160768);               //  10,485,760 (2*TT x TC bf16)

  init_x_kernel<<<(NXC+1+255)/256, 256, 0, stream>>>(hidden, x, NXC);

  for (int l=0;l<2;l++){
    // --- attention ---
    ln_kernel<<<TT, 256, 0, stream>>>(x, ln1_s + l*TC, ln1_b + l*TC, ln_f, (__hip_bfloat16*)ln_bf);
    build_qkv_bias<<<(3*TC+255)/256, 256, 0, stream>>>(q_bias + l*TC, v_bias + l*TC, qkvbias);
    cvt_kernel<<<(3*TC*TC)/2048, 256, 0, stream>>>(qkv_w + (size_t)l*3*TC*TC, wqkv, (long)3*TC*TC);
    cvt_kernel<<<(TC*TC)/2048, 256, 0, stream>>>(proj_w + (size_t)l*TC*TC, wproj, (long)TC*TC);
    gemm_bt<128,128,false,1><<<dim3(24*20,1,1), 256, 0, stream>>>(
        ln_bf, wqkv, qkv_bf, qkvbias, 0, nullptr, nullptr, 0, nullptr, nullptr,
        TT, TC, 20, 3*TC, 0,0,0,0,1);
    qkv_reshape<<<dim3(TN/128, TBH), 256, 0, stream>>>(qkv_bf, qb, kb, vT);
    gemm_bt<128,128,false,0><<<dim3(5*5,1,TBH), 256, 0, stream>>>(
        qb, kb, scores, nullptr, 0, nullptr, nullptr, 0, nullptr, nullptr,
        TN, THD, 5, TN, (long)TN*THD, (long)TN*THD, (long)TN*TN, 0, 1);
    softmax_kernel<<<TBH*TN, 256, 0, stream>>>(scores, rpb, amask, (__hip_bfloat16*)Pb);
    cvt_kernel<<<(TE*TI*TC)/2048, 256, 0, stream>>>(fc1_w + (size_t)l*TE*TI*TC, fc1b, (long)TE*TI*TC);
    gemm_bt<128,64,false,1><<<dim3(1*5,1,TBH), 256, 0, stream>>>(
        Pb, vT, attn_o, nullptr, 0, nullptr, nullptr, 0, nullptr, nullptr,
        TN, TN, 5, TC, (long)TN*TN, (long)THD*TN, (long)TN*TC, THD, TH);
    cvt_kernel<<<(TE*TC*TI)/2048, 256, 0, stream>>>(fc2_w + (size_t)l*TE*TC*TI, fc2b, (long)TE*TC*TI);
    gemm_bt<128,128,false,2><<<dim3(8*20,1,1), 256, 0, stream>>>(
        attn_o, wproj, x, proj_b + l*TC, 0, gamma1 + l*TC, nullptr, 0, nullptr, nullptr,
        TT, TC, 20, TC, 0,0,0,0,1);

    // --- MoE ---
    ln_kernel<<<TT, 256, 0, stream>>>(x, ln2_s + l*TC, ln2_b + l*TC, ln_f, (__hip_bfloat16*)ln_bf);
    gate_kernel<<<TT, 256, 0, stream>>>(ln_f, gate_w + (size_t)l*TE*TC, logits);
    hipMemsetAsync(counts, 0, TE*4, stream);
    hipMemsetAsync(psum, 0, TE*4, stream);
    routing_kernel<<<(TT+255)/256, 256, 0, stream>>>(logits, counts, etok, tE, tP, tG, psum);
    finalize_routing<<<1, 1, 0, stream>>>(counts, offsets, psum, x + NXC);
    gemm_bt<128,128,true,3><<<dim3(32*20,1,TE), 256, 0, stream>>>(
        ln_bf, fc1b, h1, fc1_b + (size_t)l*TE*TI, TI, nullptr, etok, TT, counts, offsets,
        TT, TC, 20, TI, 0, (long)TI*TC, 0, 0, 1);
    gemm_bt<128,128,false,1><<<dim3(8*20,1,TE), 256, 0, stream>>>(
        h1, fc2b, yslot, fc2_b + (size_t)l*TE*TC, TC, nullptr, nullptr, 0, counts, offsets,
        TT, TI, 20, TC, 0, (long)TC*TI, 0, 0, 1);
    combine_kernel<<<TT, 256, 0, stream>>>(yslot, tE, tP, tG, offsets, gamma2 + l*TC, x);
  }
}

// Round 6
// 1216.400 us; speedup vs baseline: 1.0889x; 1.0889x over previous
//
#include <hip/hip_runtime.h>
#include <hip/hip_bf16.h>

#define TB 4
#define TN 640
#define TC 1024
#define TH 16
#define THD 64
#define TI 4096
#define TE 8
#define TT (TB*TN)     /* 2560 tokens */
#define TBH (TB*TH)    /* 64 */
#define SCALE_ 0.125f

typedef unsigned short u16;
typedef __bf16 bf16x8 __attribute__((ext_vector_type(8)));
typedef float f32x4 __attribute__((ext_vector_type(4)));

// ---------------------------------------------------------------------------
// bf16 MFMA GEMM, minimum 2-phase pipeline (T3 recipe, m230/m248v2):
//   prologue STAGE(buf0); sync;
//   loop: STAGE(buf^1, t+1) FIRST; ds_read buf; MFMA; ONE __syncthreads.
// BK=64, both operands via global_load_lds w=16, XOR-8 source+read swizzle
// (verified conflict-free r3/r4). Compiler-managed waitcnt (no asm).
// Bijective XCD swizzle + y-fastest decode for weight L2 reuse.
// EPI: 0=store f32, 1=store bf16 (row aoff+i), 2=resadd x += v*scalevec
//      (non-atomic RMW), 3=gelu->bf16 (row aoff+i)
// Routed mode (counts != nullptr): per-z count/offset, gather rows via idx.
// ---------------------------------------------------------------------------
template<int BM, int BN, bool GATHER, int EPI>
__global__ __launch_bounds__(256) void gemm_bt(
    const u16* __restrict__ A, const u16* __restrict__ Wb, void* __restrict__ Cout,
    const float* __restrict__ bias, long biasStride,
    const float* __restrict__ scalevec,
    const int* __restrict__ idxList, long idxStride,
    const int* __restrict__ counts, const int* __restrict__ offsets,
    int M, int Kfull, int nby, int ldc,
    long sA, long sW, long sCo, long sCi, int Z2)
{
  constexpr int FM = BM/32, FN = BN/32;
  constexpr int AI = BM/32, BI = BN/32;   // 8-row chunks per wave (BK=64)

  const int ze = blockIdx.z;

  // bijective XCD swizzle (m204) + y-fastest decode
  const int nwg = gridDim.x;
  int lin = blockIdx.x;
  int q = nwg >> 3, r = nwg & 7;
  int xcd = lin & 7, pos = lin >> 3;
  int swz = (xcd < r ? xcd*(q+1) : r*(q+1) + (xcd-r)*q) + pos;
  const int bx = swz / nby;
  const int by = swz - bx*nby;

  int mcount = M, aoff = 0;
  if (counts){ mcount = counts[ze]; aoff = offsets ? offsets[ze] : 0; }
  if (by*BM >= mcount) return;

  const int tid = threadIdx.x, w = tid>>6, lane = tid&63;
  const int wm = w>>1, wn = w&1;

  __shared__ __align__(16) u16 As[2][BM*64];
  __shared__ __align__(16) u16 Bs[2][BN*64];

  const u16* Az = A + (long)ze*sA;
  const u16* Wz = Wb + (long)ze*sW;
  const int* idx_z = idxList ? (idxList + (long)ze*idxStride) : nullptr;

  const int c16 = (lane&7) ^ ((lane>>3)&7);   // swizzled 16B slot (row&7 XOR)
  long a_src[AI];
  #pragma unroll
  for (int j=0;j<AI;j++){
    int i = by*BM + (w*AI+j)*8 + (lane>>3);
    int row;
    if (counts){
      int ie = (i < mcount) ? i : (mcount-1);
      row = GATHER ? idx_z[ie] : (aoff + ie);
    } else row = i;
    a_src[j] = (long)row*Kfull + c16*8;
  }
  long b_src[BI];
  #pragma unroll
  for (int j=0;j<BI;j++){
    int rr = bx*BN + (w*BI+j)*8 + (lane>>3);
    b_src[j] = (long)rr*Kfull + c16*8;
  }

  auto STAGE = [&](int buf, int t){
    #pragma unroll
    for (int j=0;j<AI;j++)
      __builtin_amdgcn_global_load_lds(
        (const __attribute__((address_space(1))) void*)(Az + a_src[j] + t*64),
        (__attribute__((address_space(3))) void*)(&As[buf][(w*AI+j)*512]), 16, 0, 0);
    #pragma unroll
    for (int j=0;j<BI;j++)
      __builtin_amdgcn_global_load_lds(
        (const __attribute__((address_space(1))) void*)(Wz + b_src[j] + t*64),
        (__attribute__((address_space(3))) void*)(&Bs[buf][(w*BI+j)*512]), 16, 0, 0);
  };

  f32x4 acc[FM][FN];
  #pragma unroll
  for (int m=0;m<FM;m++)
    #pragma unroll
    for (int n=0;n<FN;n++) acc[m][n] = (f32x4){0.f,0.f,0.f,0.f};

  const int nt = Kfull >> 6;
  STAGE(0, 0);
  __syncthreads();
  int cur = 0;
  const int lr = lane & 15;
  const int s0 = (lane>>4) ^ (lane&7);
  const int abase = lr*128 + s0*16;     // byte offset; second half is ^64

  for (int t=0; t<nt; ++t){
    if (t+1 < nt) STAGE(cur^1, t+1);
    const char* Ab = (const char*)&As[cur][0];
    const char* Bb = (const char*)&Bs[cur][0];
    bf16x8 af[FM][2], bfr[FN][2];
    #pragma unroll
    for (int m=0;m<FM;m++){
      af[m][0] = *reinterpret_cast<const bf16x8*>(Ab + wm*(BM/2)*128 + m*2048 + abase);
      af[m][1] = *reinterpret_cast<const bf16x8*>(Ab + wm*(BM/2)*128 + m*2048 + (abase^64));
    }
    #pragma unroll
    for (int n=0;n<FN;n++){
      bfr[n][0] = *reinterpret_cast<const bf16x8*>(Bb + wn*(BN/2)*128 + n*2048 + abase);
      bfr[n][1] = *reinterpret_cast<const bf16x8*>(Bb + wn*(BN/2)*128 + n*2048 + (abase^64));
    }
    #pragma unroll
    for (int m=0;m<FM;m++)
      #pragma unroll
      for (int n=0;n<FN;n++){
        acc[m][n] = __builtin_amdgcn_mfma_f32_16x16x32_bf16(af[m][0], bfr[n][0], acc[m][n], 0,0,0);
        acc[m][n] = __builtin_amdgcn_mfma_f32_16x16x32_bf16(af[m][1], bfr[n][1], acc[m][n], 0,0,0);
      }
    __syncthreads();
    cur ^= 1;
  }

  const float* bz = bias ? (bias + (long)ze*biasStride) : nullptr;
  long csel = (long)(ze/Z2)*sCo + (long)(ze%Z2)*sCi;
  #pragma unroll
  for (int m=0;m<FM;m++){
    #pragma unroll
    for (int n=0;n<FN;n++){
      int gcol = bx*BN + wn*(BN/2) + n*16 + (lane&15);
      float bv = bz ? bz[gcol] : 0.f;
      #pragma unroll
      for (int jj=0;jj<4;jj++){
        int i = by*BM + wm*(BM/2) + m*16 + (lane>>4)*4 + jj;
        if (counts && i >= mcount) continue;
        float v = acc[m][n][jj] + bv;
        if constexpr (EPI == 0){
          ((float*)Cout)[csel + (long)i*ldc + gcol] = v;
        } else if constexpr (EPI == 1){
          ((__hip_bfloat16*)Cout)[csel + (long)(aoff+i)*ldc + gcol] = __float2bfloat16(v);
        } else if constexpr (EPI == 2){
          float* p = (float*)Cout + csel + (long)i*ldc + gcol;
          *p += v * scalevec[gcol];
        } else { // EPI == 3
          float g = 0.5f*v*(1.f + erff(v*0.70710678118654752f));
          ((__hip_bfloat16*)Cout)[csel + (long)(aoff+i)*ldc + gcol] = __float2bfloat16(g);
        }
      }
    }
  }
}

// ---------------------------------------------------------------------------
__global__ __launch_bounds__(256) void cvt_kernel(const float* __restrict__ s,
    u16* __restrict__ d, long n)
{
  long i = ((long)blockIdx.x*256 + threadIdx.x)*8;
  if (i >= n) return;
  float4 a = *(const float4*)(s+i);
  float4 b = *(const float4*)(s+i+4);
  union { __hip_bfloat162 h[4]; uint4 v; } o;
  o.h[0] = __float22bfloat162_rn(make_float2(a.x,a.y));
  o.h[1] = __float22bfloat162_rn(make_float2(a.z,a.w));
  o.h[2] = __float22bfloat162_rn(make_float2(b.x,b.y));
  o.h[3] = __float22bfloat162_rn(make_float2(b.z,b.w));
  *(uint4*)(d+i) = o.v;
}

__global__ __launch_bounds__(256) void init_x_kernel(const float* __restrict__ h,
    float* __restrict__ x, int n)
{
  int i = blockIdx.x*256 + threadIdx.x;
  if (i < n) x[i] = h[i];
  else if (i == n) x[i] = 0.f;   // aux slot
}

__global__ __launch_bounds__(256) void ln_kernel(const float* __restrict__ x,
    const float* __restrict__ s, const float* __restrict__ b,
    float* __restrict__ of, __hip_bfloat16* __restrict__ ob)
{
  int row = blockIdx.x, tid = threadIdx.x;
  const float* xr = x + (long)row*TC;
  int c = tid*4;
  float4 xv = *(const float4*)(xr + c);
  float sum = xv.x+xv.y+xv.z+xv.w;
  float sq = xv.x*xv.x+xv.y*xv.y+xv.z*xv.z+xv.w*xv.w;
  #pragma unroll
  for (int o=32;o;o>>=1){ sum += __shfl_down(sum,o); sq += __shfl_down(sq,o); }
  __shared__ float ls[8];
  if ((tid&63)==0){ ls[tid>>6] = sum; ls[4+(tid>>6)] = sq; }
  __syncthreads();
  float mean = (ls[0]+ls[1]+ls[2]+ls[3]) * (1.f/TC);
  float ex2  = (ls[4]+ls[5]+ls[6]+ls[7]) * (1.f/TC);
  float rstd = rsqrtf(ex2 - mean*mean + 1e-6f);
  float4 sv = *(const float4*)(s + c);
  float4 bv = *(const float4*)(b + c);
  float o0 = (xv.x-mean)*rstd*sv.x + bv.x;
  float o1 = (xv.y-mean)*rstd*sv.y + bv.y;
  float o2 = (xv.z-mean)*rstd*sv.z + bv.z;
  float o3 = (xv.w-mean)*rstd*sv.w + bv.w;
  *(float4*)(of + (long)row*TC + c) = make_float4(o0,o1,o2,o3);
  __hip_bfloat16* op = ob + (long)row*TC + c;
  *reinterpret_cast<__hip_bfloat162*>(op)   = __float22bfloat162_rn(make_float2(o0,o1));
  *reinterpret_cast<__hip_bfloat162*>(op+2) = __float22bfloat162_rn(make_float2(o2,o3));
}

__global__ void build_qkv_bias(const float* __restrict__ qb, const float* __restrict__ vb,
    float* __restrict__ out)
{
  int i = blockIdx.x*256 + threadIdx.x;
  if (i >= 3*TC) return;
  float v = 0.f;
  if (i < TC) v = qb[i];
  else if (i >= 2*TC) v = vb[i-2*TC];
  out[i] = v;
}

// grid (TN/128, TBH): copy q,k sections; LDS-transpose v into vT[bh][d][n]
__global__ __launch_bounds__(256) void qkv_reshape(const u16* __restrict__ qkv,
    u16* __restrict__ q, u16* __restrict__ k, u16* __restrict__ vT)
{
  const int bh = blockIdx.y, b = bh>>4, h = bh&15;
  const int n0 = blockIdx.x*128;
  const int tid = threadIdx.x;
  const long rowbase = ((long)b*TN + n0)*(3*TC) + h*THD;
  __shared__ u16 vt[128][72];
  #pragma unroll
  for (int j=0;j<4;j++){
    int f = j*2048 + tid*8;
    int r = f>>6, d = f&63;
    long src = rowbase + (long)r*(3*TC) + d;
    long dst = ((long)bh*TN + n0 + r)*THD + d;
    *(uint4*)(q + dst) = *(const uint4*)(qkv + src);
    *(uint4*)(k + dst) = *(const uint4*)(qkv + src + TC);
    *(uint4*)(&vt[r][d]) = *(const uint4*)(qkv + src + 2*TC);
  }
  __syncthreads();
  #pragma unroll
  for (int j=0;j<4;j++){
    int f = j*2048 + tid*8;
    int dr = f>>7, nc = f&127;
    union { uint4 v; u16 u[8]; } o;
    #pragma unroll
    for (int e=0;e<8;e++) o.u[e] = vt[nc+e][dr];
    *(uint4*)(vT + ((long)bh*THD + dr)*TN + n0 + nc) = o.v;
  }
}

__global__ __launch_bounds__(256) void softmax_kernel(const float* __restrict__ S,
    const float* __restrict__ rpb, const int* __restrict__ mask, __hip_bfloat16* __restrict__ P)
{
  int row = blockIdx.x, tid = threadIdx.x;
  int qpos = row % TN;
  int bh = row / TN;
  int h = bh & (TH-1);
  int b = bh >> 4;
  const float* srow = S + (long)row*TN;
  const float* rrow = rpb + ((long)h*TN + qpos)*TN;
  const int* mrow = mask + b*TN;
  float v[3];
  float mx = -3e38f;
  #pragma unroll
  for (int j=0;j<3;j++){
    int kk = tid + j*256;
    float t = -3e38f;
    if (kk < TN){
      t = srow[kk]*SCALE_ + rrow[kk];
      if (mrow[kk] == 0) t = -1e30f;
    }
    v[j] = t;
    mx = fmaxf(mx, t);
  }
  #pragma unroll
  for (int o=32;o;o>>=1) mx = fmaxf(mx, __shfl_down(mx,o));
  __shared__ float ls[4], ls2[4];
  if ((tid&63)==0) ls[tid>>6] = mx;
  __syncthreads();
  mx = fmaxf(fmaxf(ls[0],ls[1]), fmaxf(ls[2],ls[3]));
  float sum = 0.f;
  #pragma unroll
  for (int j=0;j<3;j++){
    int kk = tid + j*256;
    if (kk < TN){ v[j] = __expf(v[j]-mx); sum += v[j]; }
  }
  #pragma unroll
  for (int o=32;o;o>>=1) sum += __shfl_down(sum,o);
  if ((tid&63)==0) ls2[tid>>6] = sum;
  __syncthreads();
  float inv = 1.f/(ls2[0]+ls2[1]+ls2[2]+ls2[3]);
  #pragma unroll
  for (int j=0;j<3;j++){
    int kk = tid + j*256;
    if (kk < TN) P[(long)row*TN + kk] = __float2bfloat16(v[j]*inv);
  }
}

__global__ __launch_bounds__(256) void gate_kernel(const float* __restrict__ ln,
    const float* __restrict__ gw, float* __restrict__ logits)
{
  int t = blockIdx.x, tid = threadIdx.x;
  int c = tid*4;
  float4 xv = *(const float4*)(ln + (long)t*TC + c);
  __shared__ float ls[4];
  for (int e=0;e<TE;e++){
    float4 wv = *(const float4*)(gw + (long)e*TC + c);
    float p = xv.x*wv.x + xv.y*wv.y + xv.z*wv.z + xv.w*wv.w;
    #pragma unroll
    for (int o=32;o;o>>=1) p += __shfl_down(p,o);
    if ((tid&63)==0) ls[tid>>6] = p;
    __syncthreads();
    if (tid==0) logits[(long)t*TE + e] = ls[0]+ls[1]+ls[2]+ls[3];
    __syncthreads();
  }
}

__global__ __launch_bounds__(256) void routing_kernel(const float* __restrict__ logits,
    int* __restrict__ counts, int* __restrict__ etok,
    int* __restrict__ tE, int* __restrict__ tP, float* __restrict__ tG,
    float* __restrict__ psum)
{
  __shared__ float ps[TE];
  int tid = threadIdx.x;
  if (tid < TE) ps[tid] = 0.f;
  __syncthreads();
  int t = blockIdx.x*256 + tid;
  if (t < TT){
    float pr[TE]; float mx = -3e38f;
    #pragma unroll
    for (int e=0;e<TE;e++){ pr[e] = logits[(long)t*TE+e]; mx = fmaxf(mx, pr[e]); }
    float sum = 0.f;
    #pragma unroll
    for (int e=0;e<TE;e++){ pr[e] = __expf(pr[e]-mx); sum += pr[e]; }
    float inv = 1.f/sum;
    #pragma unroll
    for (int e=0;e<TE;e++) pr[e] *= inv;
    int i1 = 0;
    #pragma unroll
    for (int e=1;e<TE;e++) if (pr[e] > pr[i1]) i1 = e;
    int i2 = -1;
    #pragma unroll
    for (int e=0;e<TE;e++){ if (e==i1) continue; if (i2<0 || pr[e]>pr[i2]) i2=e; }
    float p1 = pr[i1], p2 = pr[i2];
    float g1 = p1/(p1+p2), g2 = p2/(p1+p2);
    int pos1 = atomicAdd(&counts[i1], 1);
    etok[i1*TT + pos1] = t;
    int pos2 = atomicAdd(&counts[i2], 1);
    etok[i2*TT + pos2] = t;
    tE[2*t] = i1; tP[2*t] = pos1; tG[2*t] = g1;
    tE[2*t+1] = i2; tP[2*t+1] = pos2; tG[2*t+1] = g2;
    #pragma unroll
    for (int e=0;e<TE;e++) atomicAdd(&ps[e], pr[e]);
  }
  __syncthreads();
  if (tid < TE) atomicAdd(&psum[tid], ps[tid]);
}

__global__ void finalize_routing(const int* __restrict__ counts, int* __restrict__ offsets,
    const float* __restrict__ psum, float* __restrict__ aux)
{
  int off = 0; float a = 0.f;
  for (int e=0;e<TE;e++){
    offsets[e] = off; off += counts[e];
    a += (psum[e]*(1.f/TT)) * ((float)counts[e]*(1.f/TT));
  }
  aux[0] += (float)TE * a;
}

// x[t] += (g1*y[slot1] + g2*y[slot2]) * gamma2   (grid TT, 256 thr, 4 col/thr)
__global__ __launch_bounds__(256) void combine_kernel(
    const u16* __restrict__ y, const int* __restrict__ tE, const int* __restrict__ tP,
    const float* __restrict__ tG, const int* __restrict__ offsets,
    const float* __restrict__ gamma2, float* __restrict__ x)
{
  int t = blockIdx.x, c = threadIdx.x*4;
  int e1 = tE[2*t], e2 = tE[2*t+1];
  long s1 = (long)(offsets[e1]+tP[2*t])*TC + c;
  long s2 = (long)(offsets[e2]+tP[2*t+1])*TC + c;
  float g1 = tG[2*t], g2 = tG[2*t+1];
  ushort4 y1 = *(const ushort4*)(y+s1);
  ushort4 y2 = *(const ushort4*)(y+s2);
  float4 gv = *(const float4*)(gamma2 + c);
  float* xp = x + (long)t*TC + c;
  float4 xv = *(const float4*)xp;
  auto b2f = [](u16 u){ union{float f;unsigned i;} v; v.i = (unsigned)u<<16; return v.f; };
  xv.x += (g1*b2f(y1.x) + g2*b2f(y2.x))*gv.x;
  xv.y += (g1*b2f(y1.y) + g2*b2f(y2.y))*gv.y;
  xv.z += (g1*b2f(y1.z) + g2*b2f(y2.z))*gv.z;
  xv.w += (g1*b2f(y1.w) + g2*b2f(y2.w))*gv.w;
  *(float4*)xp = xv;
}

// ---------------------------------------------------------------------------
extern "C" void kernel_launch(void* const* d_in, const int* in_sizes, int n_in,
                              void* d_out, int out_size, void* d_ws, size_t ws_size,
                              hipStream_t stream) {
  (void)in_sizes; (void)n_in; (void)out_size; (void)ws_size;
  const float* hidden = (const float*)d_in[0];
  const int*   amask  = (const int*)d_in[1];
  const float* rpb    = (const float*)d_in[2];
  const float* qkv_w  = (const float*)d_in[3];
  const float* q_bias = (const float*)d_in[4];
  const float* v_bias = (const float*)d_in[5];
  const float* proj_w = (const float*)d_in[6];
  const float* proj_b = (const float*)d_in[7];
  const float* ln1_s  = (const float*)d_in[8];
  const float* ln1_b  = (const float*)d_in[9];
  const float* ln2_s  = (const float*)d_in[10];
  const float* ln2_b  = (const float*)d_in[11];
  const float* gamma1 = (const float*)d_in[12];
  const float* gamma2 = (const float*)d_in[13];
  const float* gate_w = (const float*)d_in[14];
  const float* fc1_w  = (const float*)d_in[15];
  const float* fc1_b  = (const float*)d_in[16];
  const float* fc2_w  = (const float*)d_in[17];
  const float* fc2_b  = (const float*)d_in[18];

  float* x = (float*)d_out;
  const int NXC = TT*TC;

  char* p = (char*)d_ws;
  auto alloc = [&](size_t bytes)->void* {
    void* r = (void*)p; p += (bytes + 255) & ~(size_t)255; return r;
  };
  float* qkvbias = (float*)alloc(3*TC*4);
  u16*   ln_bf   = (u16*)alloc((size_t)TT*TC*2);
  float* ln_f    = (float*)alloc((size_t)TT*TC*4);
  float* logits  = (float*)alloc((size_t)TT*TE*4);
  int*   counts  = (int*)alloc(TE*4);
  int*   offsets = (int*)alloc(TE*4);
  float* psum    = (float*)alloc(TE*4);
  int*   etok    = (int*)alloc((size_t)TE*TT*4);
  int*   tE      = (int*)alloc((size_t)2*TT*4);
  int*   tP      = (int*)alloc((size_t)2*TT*4);
  float* tG      = (float*)alloc((size_t)2*TT*4);
  char* arena = (char*)alloc(202375168);
  // attention phase
  float* scores  = (float*)(arena);                         // 104,857,600
  u16*   Pb      = (u16*)(arena + 104857600);               //  52,428,800
  u16*   qkv_bf  = (u16*)(arena + 157286400);               //  15,728,640
  u16*   qb      = (u16*)(arena + 173015040);               //   5,242,880
  u16*   kb      = (u16*)(arena + 178257920);               //   5,242,880
  u16*   vT      = (u16*)(arena + 183500800);               //   5,242,880
  u16*   attn_o  = (u16*)(arena + 188743680);               //   5,242,880
  u16*   wqkv    = (u16*)(arena + 193986560);               //   6,291,456
  u16*   wproj   = (u16*)(arena + 200278016);               //   2,097,152
  // MoE phase (overlays attention-phase buffers — dead by then)
  u16*   fc1b    = (u16*)(arena);                           //  67,108,864
  u16*   fc2b    = (u16*)(arena + 67108864);                //  67,108,864
  u16*   h1      = (u16*)(arena + 134217728);               //  41,943,040 (2*TT x TI bf16)
  u16*   yslot   = (u16*)(arena + 176160768);               //  10,485,760 (2*TT x TC bf16)

  init_x_kernel<<<(NXC+1+255)/256, 256, 0, stream>>>(hidden, x, NXC);

  for (int l=0;l<2;l++){
    // --- attention ---
    ln_kernel<<<TT, 256, 0, stream>>>(x, ln1_s + l*TC, ln1_b + l*TC, ln_f, (__hip_bfloat16*)ln_bf);
    build_qkv_bias<<<(3*TC+255)/256, 256, 0, stream>>>(q_bias + l*TC, v_bias + l*TC, qkvbias);
    cvt_kernel<<<(3*TC*TC)/2048, 256, 0, stream>>>(qkv_w + (size_t)l*3*TC*TC, wqkv, (long)3*TC*TC);
    cvt_kernel<<<(TC*TC)/2048, 256, 0, stream>>>(proj_w + (size_t)l*TC*TC, wproj, (long)TC*TC);
    gemm_bt<128,128,false,1><<<dim3(24*20,1,1), 256, 0, stream>>>(
        ln_bf, wqkv, qkv_bf, qkvbias, 0, nullptr, nullptr, 0, nullptr, nullptr,
        TT, TC, 20, 3*TC, 0,0,0,0,1);
    qkv_reshape<<<dim3(TN/128, TBH), 256, 0, stream>>>(qkv_bf, qb, kb, vT);
    gemm_bt<128,128,false,0><<<dim3(5*5,1,TBH), 256, 0, stream>>>(
        qb, kb, scores, nullptr, 0, nullptr, nullptr, 0, nullptr, nullptr,
        TN, THD, 5, TN, (long)TN*THD, (long)TN*THD, (long)TN*TN, 0, 1);
    softmax_kernel<<<TBH*TN, 256, 0, stream>>>(scores, rpb, amask, (__hip_bfloat16*)Pb);
    cvt_kernel<<<(TE*TI*TC)/2048, 256, 0, stream>>>(fc1_w + (size_t)l*TE*TI*TC, fc1b, (long)TE*TI*TC);
    gemm_bt<128,64,false,1><<<dim3(1*5,1,TBH), 256, 0, stream>>>(
        Pb, vT, attn_o, nullptr, 0, nullptr, nullptr, 0, nullptr, nullptr,
        TN, TN, 5, TC, (long)TN*TN, (long)THD*TN, (long)TN*TC, THD, TH);
    cvt_kernel<<<(TE*TC*TI)/2048, 256, 0, stream>>>(fc2_w + (size_t)l*TE*TC*TI, fc2b, (long)TE*TC*TI);
    gemm_bt<64,128,false,2><<<dim3(8*40,1,1), 256, 0, stream>>>(
        attn_o, wproj, x, proj_b + l*TC, 0, gamma1 + l*TC, nullptr, 0, nullptr, nullptr,
        TT, TC, 40, TC, 0,0,0,0,1);

    // --- MoE ---
    ln_kernel<<<TT, 256, 0, stream>>>(x, ln2_s + l*TC, ln2_b + l*TC, ln_f, (__hip_bfloat16*)ln_bf);
    gate_kernel<<<TT, 256, 0, stream>>>(ln_f, gate_w + (size_t)l*TE*TC, logits);
    hipMemsetAsync(counts, 0, TE*4, stream);
    hipMemsetAsync(psum, 0, TE*4, stream);
    routing_kernel<<<(TT+255)/256, 256, 0, stream>>>(logits, counts, etok, tE, tP, tG, psum);
    finalize_routing<<<1, 1, 0, stream>>>(counts, offsets, psum, x + NXC);
    gemm_bt<128,128,true,3><<<dim3(32*20,1,TE), 256, 0, stream>>>(
        ln_bf, fc1b, h1, fc1_b + (size_t)l*TE*TI, TI, nullptr, etok, TT, counts, offsets,
        TT, TC, 20, TI, 0, (long)TI*TC, 0, 0, 1);
    gemm_bt<128,128,false,1><<<dim3(8*20,1,TE), 256, 0, stream>>>(
        h1, fc2b, yslot, fc2_b + (size_t)l*TE*TC, TC, nullptr, nullptr, 0, counts, offsets,
        TT, TI, 20, TC, 0, (long)TC*TI, 0, 0, 1);
    combine_kernel<<<TT, 256, 0, stream>>>(yslot, tE, tP, tG, offsets, gamma2 + l*TC, x);
  }
}